// Round 11
// baseline (399.648 us; speedup 1.0000x reference)
//
#include <hip/hip_runtime.h>
#include <hip/hip_bf16.h>
#include <math.h>

typedef __attribute__((ext_vector_type(8))) short bf16x8;
typedef __attribute__((ext_vector_type(4))) float f32x4;
typedef __attribute__((ext_vector_type(16))) float f32x16;

#define NBLK 512
#define L2E 1.4426950408889634f

__device__ __forceinline__ unsigned short f2bf(float f) {
  union { float f; unsigned u; } v; v.f = f;
  unsigned r = v.u + 0x7fffu + ((v.u >> 16) & 1u);
  return (unsigned short)(r >> 16);
}
__device__ __forceinline__ unsigned pack2(float lo, float hi) {
  return (unsigned)f2bf(lo) | ((unsigned)f2bf(hi) << 16);
}
__device__ __forceinline__ float bf2f(unsigned short u) {
  union { unsigned u; float f; } v; v.u = ((unsigned)u) << 16; return v.f;
}
__device__ __forceinline__ float fexp2(float x) {
#if __has_builtin(__builtin_amdgcn_exp2f)
  return __builtin_amdgcn_exp2f(x);
#else
  return exp2f(x);
#endif
}
__device__ __forceinline__ unsigned cvtpk(float lo, float hi) {
  unsigned r;
  asm("v_cvt_pk_bf16_f32 %0, %1, %2" : "=v"(r) : "v"(lo), "v"(hi));
  return r;
}
__device__ __forceinline__ void gload16(const void* gsrc, void* lds) {
  __builtin_amdgcn_global_load_lds(
      (const __attribute__((address_space(1))) unsigned int*)gsrc,
      (__attribute__((address_space(3))) unsigned int*)lds, 16, 0, 0);
}
#if __has_builtin(__builtin_amdgcn_permlane32_swap)
typedef __attribute__((ext_vector_type(2))) unsigned u32x2;
__device__ __forceinline__ void plswap(unsigned& a, unsigned& b) {
  u32x2 r = __builtin_amdgcn_permlane32_swap(a, b, false, false);
  a = r[0]; b = r[1];
}
#else
__device__ __forceinline__ void plswap(unsigned& a, unsigned& b) {
  unsigned as = (unsigned)__shfl_xor((int)a, 32, 64);
  unsigned bs = (unsigned)__shfl_xor((int)b, 32, 64);
  bool hi = (threadIdx.x & 32) != 0;
  unsigned na = hi ? bs : a;
  unsigned nb = hi ? b : as;
  a = na; b = nb;
}
#endif

__device__ __forceinline__ int xcd_swz(int p, int cpx) {
  return (p & 7) * cpx + (p >> 3);
}

// Grid-wide sense barrier. Safe iff all NBLK blocks co-resident
// (guaranteed: 512 blocks, launch_bounds(256,2) -> >=2 blocks/CU x 256 CU).
__device__ __forceinline__ void gsync(unsigned* cnt, unsigned* gen) {
  __syncthreads();
  if (threadIdx.x == 0) {
    __threadfence();  // release: make this block's stores agent-visible
    unsigned g = __hip_atomic_load(gen, __ATOMIC_RELAXED, __HIP_MEMORY_SCOPE_AGENT);
    unsigned old = __hip_atomic_fetch_add(cnt, 1u, __ATOMIC_ACQ_REL, __HIP_MEMORY_SCOPE_AGENT);
    if (old == NBLK - 1) {
      __hip_atomic_store(cnt, 0u, __ATOMIC_RELAXED, __HIP_MEMORY_SCOPE_AGENT);
      __hip_atomic_fetch_add(gen, 1u, __ATOMIC_RELEASE, __HIP_MEMORY_SCOPE_AGENT);
    } else {
      while (__hip_atomic_load(gen, __ATOMIC_ACQUIRE, __HIP_MEMORY_SCOPE_AGENT) == g)
        __builtin_amdgcn_s_sleep(8);
    }
    __threadfence();  // acquire: see other blocks' stores
  }
  __syncthreads();
}

// ---------------------------------------------------------------------------
// Phase 0: prep (weights f32->bf16, hs f32->bf16, physics ext slabs).
// 2048 virtual blocks -> 4 per real block.
// ---------------------------------------------------------------------------
__device__ void prep_phase(int p, int tid, const float* hs, const float* phi,
                           const float* mag, const float* mask,
                           const float* gamma, const float* Wq, const float* Wk,
                           const float* Wv, const float* Wo, const float* W1,
                           const float* W2, unsigned short* wts,
                           unsigned short* hsb, unsigned short* qx,
                           unsigned short* kx) {
#pragma unroll
  for (int jj = 0; jj < 4; jj++) {
    int blk = p * 4 + jj;
    if (blk < 768) {
      int i = blk * 1024 + tid * 4;
      const float* src; int off;
      if (i < 262144) {
        src = (i < 131072) ? (i < 65536 ? Wq : Wk) : (i < 196608 ? Wv : Wo);
        off = i & 65535;
      } else if (i < 524288) { src = W1; off = i - 262144; }
      else { src = W2; off = i - 524288; }
      float4 v = *(const float4*)&src[off];
      *(uint2*)&wts[i] = make_uint2(pack2(v.x, v.y), pack2(v.z, v.w));
    } else if (blk < 1792) {
      int i = (blk - 768) * 2048 + tid * 8;
      const float4* hp = (const float4*)hs;
      float4 a = hp[i >> 2], b = hp[(i >> 2) + 1];
      *(uint4*)&hsb[i] = make_uint4(pack2(a.x, a.y), pack2(a.z, a.w),
                                    pack2(b.x, b.y), pack2(b.z, b.w));
    } else {
      int row = (blk - 1792) * 256 + tid;
      int bh = row >> 10, key = row & 1023, b = row >> 13, h = (row >> 10) & 7;
      float pphi = phi[row], mg = mag[row];
      float sn, cs; sincosf(pphi, &sn, &cs);
      float c = mg * cs, s = mg * sn;
      float msk = mask[b * 1024 + key];
      int ch = key >> 5, k32 = key & 31;
      size_t base = ((((size_t)(bh * 32 + ch) * 3 + 2) * 2 + 0) * 32 + k32) * 8;
      *(uint4*)&kx[base] = make_uint4(pack2(c, s), pack2(msk, 0.0f), 0u, 0u);
      *(uint4*)&kx[base + 256] = make_uint4(0u, 0u, 0u, 0u);
      float g = gamma[h];
      *(uint4*)&qx[base] = make_uint4(pack2(L2E * g * c, L2E * g * s),
                                      pack2(L2E, 0.0f), 0u, 0u);
      *(uint4*)&qx[base + 256] = make_uint4(0u, 0u, 0u, 0u);
    }
  }
}

// ---------------------------------------------------------------------------
// Phase 1: fused QKV GEMM (384 work items; blocks >=384 idle).
// ---------------------------------------------------------------------------
__device__ void qkv_phase(void* smemv, int w_id, int tid,
                          const unsigned short* A, const unsigned short* wts,
                          const float* bq, const float* bk, const float* bv,
                          unsigned short* qx, unsigned short* kx,
                          unsigned short* vt2) {
  unsigned short* As = (unsigned short*)smemv;
  unsigned short* Bs = As + 8192;
  const int xw = w_id % 6;
  const int mat = xw >> 1;
  const int n0 = (xw & 1) * 128;
  const int m0 = (w_id / 6) * 128;
  const unsigned short* W = wts + mat * 65536;
  const float* bias = (mat == 0) ? bq : ((mat == 1) ? bk : bv);
  const int wm = (tid >> 7) & 1, wn = (tid >> 6) & 1;
  const int g = (tid >> 4) & 3, c = tid & 15;
  const int l = tid & 63, wv = tid >> 6;
  const int rr = l >> 3, scol = ((l & 7) ^ rr) << 3;
  const unsigned short* aSrc = &A[(size_t)(m0 + wv * 32 + rr) * 256 + scol];
  const unsigned short* bSrc = &W[(size_t)(n0 + wv * 32 + rr) * 256 + scol];
  unsigned short* aDst = &As[wv * 32 * 64];
  unsigned short* bDst = &Bs[wv * 32 * 64];
  f32x4 acc[4][4] = {};
  for (int k0 = 0; k0 < 256; k0 += 64) {
    __syncthreads();
#pragma unroll
    for (int i = 0; i < 4; i++) {
      gload16(aSrc + (size_t)i * 8 * 256 + k0, aDst + i * 8 * 64);
      gload16(bSrc + (size_t)i * 8 * 256 + k0, bDst + i * 8 * 64);
    }
    __syncthreads();
#pragma unroll
    for (int kk = 0; kk < 2; kk++) {
      bf16x8 af[4], bfr[4];
#pragma unroll
      for (int mi = 0; mi < 4; mi++) {
        int row = wm * 64 + mi * 16 + c;
        af[mi] = *(const bf16x8*)&As[row * 64 + (((g + 4 * kk) ^ (row & 7)) << 3)];
      }
#pragma unroll
      for (int ni = 0; ni < 4; ni++) {
        int row = wn * 64 + ni * 16 + c;
        bfr[ni] = *(const bf16x8*)&Bs[row * 64 + (((g + 4 * kk) ^ (row & 7)) << 3)];
      }
#pragma unroll
      for (int mi = 0; mi < 4; mi++)
#pragma unroll
        for (int ni = 0; ni < 4; ni++)
          acc[mi][ni] = __builtin_amdgcn_mfma_f32_16x16x32_bf16(af[mi], bfr[ni], acc[mi][ni], 0, 0, 0);
    }
  }
  const float scale = (mat == 0) ? (L2E * 0.17677669529663687f) : 1.0f;
#pragma unroll
  for (int ni = 0; ni < 4; ni++) {
    int n = n0 + wn * 64 + ni * 16 + c;
    float bv_ = bias[n];
    int h = n >> 5, dd = n & 31;
#pragma unroll
    for (int mi = 0; mi < 4; mi++) {
      int mbase = m0 + wm * 64 + mi * 16 + 4 * g;
      int bb = mbase >> 10, rowL = mbase & 1023;
      int bh = bb * 8 + h;
      if (mat < 2) {
        unsigned short* out = (mat == 0) ? qx : kx;
        int m_idx = dd >> 4, hi = (dd >> 3) & 1, j = dd & 7;
#pragma unroll
        for (int r = 0; r < 4; r++) {
          int keyL = rowL + r;
          int ch = keyL >> 5, k32 = keyL & 31;
          out[(((((size_t)bh * 32 + ch) * 3 + m_idx) * 2 + hi) * 32 + k32) * 8 + j] =
              f2bf((acc[mi][ni][r] + bv_) * scale);
        }
      } else {
        int keyL = rowL;
        int ch = keyL >> 5, t = (keyL >> 4) & 1, hi = (keyL >> 3) & 1;
        size_t base = (((((size_t)bh * 32 + ch) * 2 + t) * 2 + hi) * 32 + dd) * 8 + (g & 1) * 4;
        *(uint2*)&vt2[base] =
            make_uint2(pack2(acc[mi][ni][0] + bv_, acc[mi][ni][1] + bv_),
                       pack2(acc[mi][ni][2] + bv_, acc[mi][ni][3] + bv_));
      }
    }
  }
}

// ---------------------------------------------------------------------------
// Phase 2: attention (32x32x16 MFMA, physics in ext dims, no LDS).
// ---------------------------------------------------------------------------
__device__ void attn_phase(int w_id, int tid, const unsigned short* qx,
                           const unsigned short* kx, const unsigned short* vt2,
                           unsigned short* ctx) {
  const int wave = tid >> 6, lane = tid & 63;
  const int hi = lane >> 5, l31 = lane & 31;
  const int bh = w_id >> 3, bb = bh >> 3, h = bh & 7;
  const int qch = (w_id & 7) * 4 + wave;

  const size_t qoff = (((size_t)(bh * 32 + qch) * 3 * 2 + hi) * 32 + l31) * 8;
  bf16x8 qf0 = *(const bf16x8*)&qx[qoff];
  bf16x8 qf1 = *(const bf16x8*)&qx[qoff + 512];
  bf16x8 qf2 = *(const bf16x8*)&qx[qoff + 1024];

  f32x16 acc = {};
  float mrun = 0.0f, lsum = 0.0f;

  for (int ch = 0; ch < 32; ch++) {
    const size_t koff = (((size_t)(bh * 32 + ch) * 3 * 2 + hi) * 32 + l31) * 8;
    bf16x8 kf0 = *(const bf16x8*)&kx[koff];
    bf16x8 kf1 = *(const bf16x8*)&kx[koff + 512];
    bf16x8 kf2 = *(const bf16x8*)&kx[koff + 1024];
    const size_t voff = (((size_t)(bh * 32 + ch) * 2 * 2 + hi) * 32 + l31) * 8;
    bf16x8 vf0 = *(const bf16x8*)&vt2[voff];
    bf16x8 vf1 = *(const bf16x8*)&vt2[voff + 512];

    f32x16 s = {};
    __builtin_amdgcn_s_setprio(1);
    s = __builtin_amdgcn_mfma_f32_32x32x16_bf16(kf0, qf0, s, 0, 0, 0);
    s = __builtin_amdgcn_mfma_f32_32x32x16_bf16(kf1, qf1, s, 0, 0, 0);
    s = __builtin_amdgcn_mfma_f32_32x32x16_bf16(kf2, qf2, s, 0, 0, 0);
    __builtin_amdgcn_s_setprio(0);

    float pm = fmaxf(fmaxf(fmaxf(s[0], s[1]), fmaxf(s[2], s[3])),
                     fmaxf(fmaxf(s[4], s[5]), fmaxf(s[6], s[7])));
    pm = fmaxf(pm, fmaxf(fmaxf(fmaxf(s[8], s[9]), fmaxf(s[10], s[11])),
                         fmaxf(fmaxf(s[12], s[13]), fmaxf(s[14], s[15]))));
    pm = fmaxf(pm, __shfl_xor(pm, 32, 64));
    if (__any(pm > mrun + 12.0f)) {
      float mn = fmaxf(mrun, pm);
      float rs = fexp2(mrun - mn);
      lsum *= rs;
      mrun = mn;
#pragma unroll
      for (int r = 0; r < 16; r++) {
        float rr = __shfl(rs, (r & 3) + 8 * (r >> 2) + 4 * hi, 64);
        acc[r] *= rr;
      }
    }
    float p[16];
#pragma unroll
    for (int r = 0; r < 16; r++) p[r] = fexp2(s[r] - mrun);
    lsum += (((p[0] + p[1]) + (p[2] + p[3])) + ((p[4] + p[5]) + (p[6] + p[7]))) +
            (((p[8] + p[9]) + (p[10] + p[11])) + ((p[12] + p[13]) + (p[14] + p[15])));
    unsigned u0 = cvtpk(p[0], p[1]), u1 = cvtpk(p[2], p[3]);
    unsigned u2 = cvtpk(p[4], p[5]), u3 = cvtpk(p[6], p[7]);
    plswap(u0, u2); plswap(u1, u3);
    unsigned u4 = cvtpk(p[8], p[9]), u5 = cvtpk(p[10], p[11]);
    unsigned u6 = cvtpk(p[12], p[13]), u7 = cvtpk(p[14], p[15]);
    plswap(u4, u6); plswap(u5, u7);
    union { unsigned u[4]; bf16x8 v; } A1, A2;
    A1.u[0] = u0; A1.u[1] = u1; A1.u[2] = u2; A1.u[3] = u3;
    A2.u[0] = u4; A2.u[1] = u5; A2.u[2] = u6; A2.u[3] = u7;
    __builtin_amdgcn_s_setprio(1);
    acc = __builtin_amdgcn_mfma_f32_32x32x16_bf16(A1.v, vf0, acc, 0, 0, 0);
    acc = __builtin_amdgcn_mfma_f32_32x32x16_bf16(A2.v, vf1, acc, 0, 0, 0);
    __builtin_amdgcn_s_setprio(0);
  }
  lsum += __shfl_xor(lsum, 32, 64);
  float inv = 1.0f / lsum;
#pragma unroll
  for (int r = 0; r < 16; r++) {
    int qr = (r & 3) + 8 * (r >> 2) + 4 * hi;
    float rr = __shfl(inv, qr, 64);
    ctx[((size_t)bb * 1024 + qch * 32 + qr) * 256 + h * 32 + l31] = f2bf(acc[r] * rr);
  }
}

// ---------------------------------------------------------------------------
// Phase 3/5: GEMM + bias + residual + LayerNorm. BM=16, BN=256 (full rows),
// 4 waves x 64 cols, 2 blocks/CU (validated R9 recipe at mega residency).
// ---------------------------------------------------------------------------
template <int KD, int RESBF, int OUTBF>
__device__ void gemm_ln_phase(void* smemv, int wid, int tid,
                              const unsigned short* A, const unsigned short* W,
                              const float* bias, const void* resid,
                              const float* lng, const float* lnb, void* out) {
  unsigned short* As = (unsigned short*)smemv;  // 16x64
  unsigned short* Bs = As + 1024;               // 256x64
  float* red = (float*)(Bs + 16384);            // 128 floats
  const int m0 = wid * 16;
  const int w = tid >> 6, l = tid & 63;
  const int g = (l >> 4) & 3, c = l & 15;
  const int rr = l >> 3, scol = ((l & 7) ^ rr) << 3;
  const unsigned short* aSrc = &A[(size_t)(m0 + rr) * KD + scol];
  const unsigned short* bSrc = &W[(size_t)(w * 64 + rr) * KD + scol];
  unsigned short* bDst = Bs + w * 64 * 64;
  f32x4 acc[4] = {};
  for (int k0 = 0; k0 < KD; k0 += 64) {
    __syncthreads();
    if (w == 0) {
      gload16(aSrc + k0, &As[0]);
      gload16(aSrc + (size_t)8 * KD + k0, &As[8 * 64]);
    }
#pragma unroll
    for (int i = 0; i < 8; i++)
      gload16(bSrc + (size_t)i * 8 * KD + k0, bDst + i * 8 * 64);
    __syncthreads();
#pragma unroll
    for (int kk = 0; kk < 2; kk++) {
      bf16x8 af = *(const bf16x8*)&As[c * 64 + (((g + 4 * kk) ^ (c & 7)) << 3)];
#pragma unroll
      for (int ni = 0; ni < 4; ni++) {
        int row = w * 64 + ni * 16 + c;
        bf16x8 bfr = *(const bf16x8*)&Bs[row * 64 + (((g + 4 * kk) ^ (row & 7)) << 3)];
        acc[ni] = __builtin_amdgcn_mfma_f32_16x16x32_bf16(af, bfr, acc[ni], 0, 0, 0);
      }
    }
  }
  float x[4][4], s1[4], s2[4];
#pragma unroll
  for (int r = 0; r < 4; r++) { s1[r] = 0.0f; s2[r] = 0.0f; }
#pragma unroll
  for (int ni = 0; ni < 4; ni++) {
    int n = w * 64 + ni * 16 + c;
    float bv_ = bias[n];
#pragma unroll
    for (int r = 0; r < 4; r++) {
      int m = m0 + 4 * g + r;
      float rv = RESBF
          ? bf2f(((const unsigned short*)resid)[(size_t)m * 256 + n])
          : ((const float*)resid)[(size_t)m * 256 + n];
      float v = acc[ni][r] + bv_ + rv;
      x[ni][r] = v;
      s1[r] += v;
      s2[r] += v * v;
    }
  }
#pragma unroll
  for (int off = 1; off < 16; off <<= 1) {
#pragma unroll
    for (int r = 0; r < 4; r++) {
      s1[r] += __shfl_xor(s1[r], off, 64);
      s2[r] += __shfl_xor(s2[r], off, 64);
    }
  }
  if (c == 0) {
#pragma unroll
    for (int r = 0; r < 4; r++) {
      red[w * 16 + 4 * g + r] = s1[r];
      red[64 + w * 16 + 4 * g + r] = s2[r];
    }
  }
  __syncthreads();
#pragma unroll
  for (int r = 0; r < 4; r++) {
    int row = 4 * g + r;
    float t1 = (red[row] + red[16 + row]) + (red[32 + row] + red[48 + row]);
    float t2 = (red[64 + row] + red[80 + row]) + (red[96 + row] + red[112 + row]);
    float mean = t1 * (1.0f / 256.0f);
    float var = fmaxf(t2 * (1.0f / 256.0f) - mean * mean, 0.0f);
    float istd = rsqrtf(var + 1e-12f);
    int m = m0 + row;
#pragma unroll
    for (int ni = 0; ni < 4; ni++) {
      int n = w * 64 + ni * 16 + c;
      float o = (x[ni][r] - mean) * istd * lng[n] + lnb[n];
      if (OUTBF)
        ((unsigned short*)out)[(size_t)m * 256 + n] = f2bf(o);
      else
        ((float*)out)[(size_t)m * 256 + n] = o;
    }
  }
}

// ---------------------------------------------------------------------------
// Phase 4: FFN1 GEMM (BM=128, BN=128, gelu, bf16 out).
// ---------------------------------------------------------------------------
__device__ void ffn1_phase(void* smemv, int w_id, int tid,
                           const unsigned short* A, const unsigned short* W,
                           const float* bias, unsigned short* Cout) {
  unsigned short* As = (unsigned short*)smemv;
  unsigned short* Bs = As + 8192;
  const int n0 = (w_id % 8) * 128;
  const int m0 = (w_id / 8) * 128;
  const int wm = (tid >> 7) & 1, wn = (tid >> 6) & 1;
  const int g = (tid >> 4) & 3, c = tid & 15;
  const int l = tid & 63, wv = tid >> 6;
  const int rr = l >> 3, scol = ((l & 7) ^ rr) << 3;
  const unsigned short* aSrc = &A[(size_t)(m0 + wv * 32 + rr) * 256 + scol];
  const unsigned short* bSrc = &W[(size_t)(n0 + wv * 32 + rr) * 256 + scol];
  unsigned short* aDst = &As[wv * 32 * 64];
  unsigned short* bDst = &Bs[wv * 32 * 64];
  f32x4 acc[4][4] = {};
  for (int k0 = 0; k0 < 256; k0 += 64) {
    __syncthreads();
#pragma unroll
    for (int i = 0; i < 4; i++) {
      gload16(aSrc + (size_t)i * 8 * 256 + k0, aDst + i * 8 * 64);
      gload16(bSrc + (size_t)i * 8 * 256 + k0, bDst + i * 8 * 64);
    }
    __syncthreads();
#pragma unroll
    for (int kk = 0; kk < 2; kk++) {
      bf16x8 af[4], bfr[4];
#pragma unroll
      for (int mi = 0; mi < 4; mi++) {
        int row = wm * 64 + mi * 16 + c;
        af[mi] = *(const bf16x8*)&As[row * 64 + (((g + 4 * kk) ^ (row & 7)) << 3)];
      }
#pragma unroll
      for (int ni = 0; ni < 4; ni++) {
        int row = wn * 64 + ni * 16 + c;
        bfr[ni] = *(const bf16x8*)&Bs[row * 64 + (((g + 4 * kk) ^ (row & 7)) << 3)];
      }
#pragma unroll
      for (int mi = 0; mi < 4; mi++)
#pragma unroll
        for (int ni = 0; ni < 4; ni++)
          acc[mi][ni] = __builtin_amdgcn_mfma_f32_16x16x32_bf16(af[mi], bfr[ni], acc[mi][ni], 0, 0, 0);
    }
  }
#pragma unroll
  for (int ni = 0; ni < 4; ni++) {
    int n = n0 + wn * 64 + ni * 16 + c;
    float bv_ = bias[n];
#pragma unroll
    for (int mi = 0; mi < 4; mi++) {
      int mbase = m0 + wm * 64 + mi * 16 + 4 * g;
#pragma unroll
      for (int r = 0; r < 4; r++) {
        int m = mbase + r;
        float x = acc[mi][ni][r] + bv_;
        Cout[(size_t)m * 1024 + n] =
            f2bf(x * 0.5f * (1.0f + erff(x * 0.70710678118654752f)));
      }
    }
  }
}

// ---------------------------------------------------------------------------
// The mega-kernel: all 6 phases, grid 512 x 256, 5 grid-wide barriers.
// ---------------------------------------------------------------------------
__global__ __launch_bounds__(256, 2) void mega(
    const float* __restrict__ hs, const float* __restrict__ mask,
    const float* __restrict__ phi, const float* __restrict__ mag,
    const float* __restrict__ gamma, const float* __restrict__ Wq,
    const float* __restrict__ Wk, const float* __restrict__ Wv,
    const float* __restrict__ Wo, const float* __restrict__ W1,
    const float* __restrict__ W2, const float* __restrict__ bq,
    const float* __restrict__ bk, const float* __restrict__ bv,
    const float* __restrict__ bo, const float* __restrict__ b1,
    const float* __restrict__ b2, const float* __restrict__ ln1g,
    const float* __restrict__ ln1b, const float* __restrict__ ln2g,
    const float* __restrict__ ln2b, unsigned short* __restrict__ wts,
    unsigned short* __restrict__ hsb, unsigned short* __restrict__ qx,
    unsigned short* __restrict__ kx, unsigned short* __restrict__ vt2,
    unsigned short* __restrict__ ctx, unsigned short* __restrict__ aout,
    unsigned short* __restrict__ hbuf, float* __restrict__ out,
    unsigned* __restrict__ bar) {
  __shared__ __align__(16) char smem[35328];
  const int p = blockIdx.x, tid = threadIdx.x;
  unsigned* cnt = bar;
  unsigned* gen = bar + 64;

  // P0: prep
  prep_phase(p, tid, hs, phi, mag, mask, gamma, Wq, Wk, Wv, Wo, W1, W2, wts,
             hsb, qx, kx);
  gsync(cnt, gen);
  // P1: QKV
  if (p < 384)
    qkv_phase(smem, xcd_swz(p, 48), tid, hsb, wts, bq, bk, bv, qx, kx, vt2);
  gsync(cnt, gen);
  // P2: attention
  attn_phase(xcd_swz(p, 64), tid, qx, kx, vt2, ctx);
  gsync(cnt, gen);
  // P3: Wo + residual(hs) + LN1 -> aout (bf16)
  gemm_ln_phase<256, 0, 1>(smem, xcd_swz(p, 64), tid, ctx, wts + 196608, bo,
                           hs, ln1g, ln1b, aout);
  gsync(cnt, gen);
  // P4: FFN1 + gelu -> hbuf (bf16)
  ffn1_phase(smem, xcd_swz(p, 64), tid, aout, wts + 262144, b1, hbuf);
  gsync(cnt, gen);
  // P5: FFN2 + residual(aout) + LN2 -> out (f32)
  gemm_ln_phase<1024, 1, 0>(smem, xcd_swz(p, 64), tid, hbuf, wts + 524288, b2,
                            aout, ln2g, ln2b, out);
}

// ---------------------------------------------------------------------------
extern "C" void kernel_launch(void* const* d_in, const int* in_sizes, int n_in,
                              void* d_out, int out_size, void* d_ws,
                              size_t ws_size, hipStream_t stream) {
  const float* hs = (const float*)d_in[0];
  const float* mask = (const float*)d_in[1];
  const float* phi = (const float*)d_in[2];
  const float* mag = (const float*)d_in[3];
  const float* Wq = (const float*)d_in[4];
  const float* bq = (const float*)d_in[5];
  const float* Wk = (const float*)d_in[6];
  const float* bk = (const float*)d_in[7];
  const float* Wv = (const float*)d_in[8];
  const float* bv = (const float*)d_in[9];
  const float* Wo = (const float*)d_in[10];
  const float* bo = (const float*)d_in[11];
  const float* ln1g = (const float*)d_in[12];
  const float* ln1b = (const float*)d_in[13];
  const float* gamma = (const float*)d_in[14];
  const float* W1 = (const float*)d_in[15];
  const float* b1 = (const float*)d_in[16];
  const float* W2 = (const float*)d_in[17];
  const float* b2 = (const float*)d_in[18];
  const float* ln2g = (const float*)d_in[19];
  const float* ln2b = (const float*)d_in[20];

  char* wsb = (char*)d_ws;
  unsigned short* wts = (unsigned short*)(wsb + 0);              // 1.5MB
  unsigned short* hsb = (unsigned short*)(wsb + (2ull << 20));   // 4MB
  unsigned short* ctx = (unsigned short*)(wsb + (6ull << 20));   // 4MB
  unsigned short* aout = (unsigned short*)(wsb + (10ull << 20)); // 4MB
  unsigned short* qx = (unsigned short*)(wsb + (22ull << 20));   // 6MB
  unsigned short* kx = (unsigned short*)(wsb + (28ull << 20));   // 6MB
  unsigned short* vt2 = (unsigned short*)(wsb + (34ull << 20));  // 4MB
  unsigned short* hbuf = (unsigned short*)(wsb + (22ull << 20)); // 16MB (reuse)
  unsigned* bar = (unsigned*)(wsb + (40ull << 20));              // 512B

  hipMemsetAsync(bar, 0, 512, stream);
  mega<<<dim3(NBLK), dim3(256), 0, stream>>>(
      hs, mask, phi, mag, gamma, Wq, Wk, Wv, Wo, W1, W2, bq, bk, bv, bo, b1,
      b2, ln1g, ln1b, ln2g, ln2b, wts, hsb, qx, kx, vt2, ctx, aout, hbuf,
      (float*)d_out, bar);
}

// Round 12
// 90.744 us; speedup vs baseline: 4.4041x; 4.4041x over previous
//
#include <hip/hip_runtime.h>
#include <hip/hip_bf16.h>
#include <math.h>

typedef __attribute__((ext_vector_type(8))) short bf16x8;
typedef __attribute__((ext_vector_type(4))) float f32x4;
typedef __attribute__((ext_vector_type(16))) float f32x16;

#define L2E 1.4426950408889634f

__device__ __forceinline__ unsigned short f2bf(float f) {
  union { float f; unsigned u; } v; v.f = f;
  unsigned r = v.u + 0x7fffu + ((v.u >> 16) & 1u);
  return (unsigned short)(r >> 16);
}
__device__ __forceinline__ unsigned pack2(float lo, float hi) {
  return (unsigned)f2bf(lo) | ((unsigned)f2bf(hi) << 16);
}
__device__ __forceinline__ float bf2f(unsigned short u) {
  union { unsigned u; float f; } v; v.u = ((unsigned)u) << 16; return v.f;
}
__device__ __forceinline__ float fexp2(float x) {
#if __has_builtin(__builtin_amdgcn_exp2f)
  return __builtin_amdgcn_exp2f(x);
#else
  return exp2f(x);
#endif
}
__device__ __forceinline__ unsigned cvtpk(float lo, float hi) {
  unsigned r;
  asm("v_cvt_pk_bf16_f32 %0, %1, %2" : "=v"(r) : "v"(lo), "v"(hi));
  return r;
}
__device__ __forceinline__ uint4 pack8(float4 a, float4 b) {
  return make_uint4(pack2(a.x, a.y), pack2(a.z, a.w), pack2(b.x, b.y),
                    pack2(b.z, b.w));
}
// global -> LDS direct copy, 16B per lane; lds dest must be wave-uniform base.
__device__ __forceinline__ void gload16(const void* gsrc, void* lds) {
  __builtin_amdgcn_global_load_lds(
      (const __attribute__((address_space(1))) unsigned int*)gsrc,
      (__attribute__((address_space(3))) unsigned int*)lds, 16, 0, 0);
}
#if __has_builtin(__builtin_amdgcn_permlane32_swap)
typedef __attribute__((ext_vector_type(2))) unsigned u32x2;
__device__ __forceinline__ void plswap(unsigned& a, unsigned& b) {
  u32x2 r = __builtin_amdgcn_permlane32_swap(a, b, false, false);
  a = r[0]; b = r[1];
}
#else
__device__ __forceinline__ void plswap(unsigned& a, unsigned& b) {
  unsigned as = (unsigned)__shfl_xor((int)a, 32, 64);
  unsigned bs = (unsigned)__shfl_xor((int)b, 32, 64);
  bool hi = (threadIdx.x & 32) != 0;
  unsigned na = hi ? bs : a;
  unsigned nb = hi ? b : as;
  a = na; b = nb;
}
#endif

// XCD-aware bijective swizzle (nwg % 8 == 0): physical block p -> work id.
__device__ __forceinline__ int xcd_swz(int p, int cpx) {
  return (p & 7) * cpx + (p >> 3);
}

// ---------------------------------------------------------------------------
// Fused QKV GEMM (f32 in, pack-on-stage, bf16 MFMA) + physics ext-slab fill.
// grid 448: p<384 -> gemm (XCD-swizzled); p>=384 -> slab fill (64 blocks).
// ---------------------------------------------------------------------------
__global__ __launch_bounds__(256) void gemm_qkv(
    const float* __restrict__ A, const float* __restrict__ Wq,
    const float* __restrict__ Wk, const float* __restrict__ Wv,
    const float* __restrict__ bq, const float* __restrict__ bk,
    const float* __restrict__ bv, const float* __restrict__ phi,
    const float* __restrict__ mag, const float* __restrict__ mask,
    const float* __restrict__ gamma, unsigned short* __restrict__ qx,
    unsigned short* __restrict__ kx, unsigned short* __restrict__ vt2) {
  const int tid = threadIdx.x;
  const int p = blockIdx.x;
  if (p >= 384) {  // physics ext slabs: block handles bh = p-384
    const int bh = p - 384, b = bh >> 3, h = bh & 7;
    const float gm = gamma[h];
#pragma unroll
    for (int rr = 0; rr < 4; rr++) {
      int key = tid * 4 + rr;
      int row = bh * 1024 + key;
      float pp = phi[row], mg = mag[row];
      float sn, cs; sincosf(pp, &sn, &cs);
      float c = mg * cs, s = mg * sn;
      float msk = mask[b * 1024 + key];
      int ch = key >> 5, k32 = key & 31;
      size_t base = ((((size_t)(bh * 32 + ch) * 3 + 2) * 2 + 0) * 32 + k32) * 8;
      *(uint4*)&kx[base] = make_uint4(pack2(c, s), pack2(msk, 0.0f), 0u, 0u);
      *(uint4*)&kx[base + 256] = make_uint4(0u, 0u, 0u, 0u);
      *(uint4*)&qx[base] = make_uint4(pack2(L2E * gm * c, L2E * gm * s),
                                      pack2(L2E, 0.0f), 0u, 0u);
      *(uint4*)&qx[base + 256] = make_uint4(0u, 0u, 0u, 0u);
    }
    return;
  }
  __shared__ __align__(16) unsigned short As[128 * 64];
  __shared__ __align__(16) unsigned short Bs[128 * 64];
  const int w_id = xcd_swz(p, 48);
  const int xw = w_id % 6;
  const int mat = xw >> 1;
  const int n0 = (xw & 1) * 128;
  const int m0 = (w_id / 6) * 128;
  const float* W = (mat == 0) ? Wq : ((mat == 1) ? Wk : Wv);
  const float* bias = (mat == 0) ? bq : ((mat == 1) ? bk : bv);
  const int wm = (tid >> 7) & 1, wn = (tid >> 6) & 1;
  const int g = (tid >> 4) & 3, c = tid & 15;
  f32x4 acc[4][4] = {};
  for (int k0 = 0; k0 < 256; k0 += 64) {
    __syncthreads();
#pragma unroll
    for (int i = 0; i < 4; i++) {
      int idx = tid * 8 + i * 2048;
      int r = idx >> 6, c8 = idx & 63;
      const float* ap = &A[(size_t)(m0 + r) * 256 + k0 + c8];
      const float* wp = &W[(size_t)(n0 + r) * 256 + k0 + c8];
      float4 a0 = *(const float4*)ap, a1 = *(const float4*)(ap + 4);
      float4 w0 = *(const float4*)wp, w1 = *(const float4*)(wp + 4);
      int dst = r * 64 + (((c8 >> 3) ^ (r & 7)) << 3);
      *(uint4*)&As[dst] = pack8(a0, a1);
      *(uint4*)&Bs[dst] = pack8(w0, w1);
    }
    __syncthreads();
#pragma unroll
    for (int kk = 0; kk < 2; kk++) {
      bf16x8 af[4], bfr[4];
#pragma unroll
      for (int mi = 0; mi < 4; mi++) {
        int row = wm * 64 + mi * 16 + c;
        af[mi] = *(const bf16x8*)&As[row * 64 + (((g + 4 * kk) ^ (row & 7)) << 3)];
      }
#pragma unroll
      for (int ni = 0; ni < 4; ni++) {
        int row = wn * 64 + ni * 16 + c;
        bfr[ni] = *(const bf16x8*)&Bs[row * 64 + (((g + 4 * kk) ^ (row & 7)) << 3)];
      }
#pragma unroll
      for (int mi = 0; mi < 4; mi++)
#pragma unroll
        for (int ni = 0; ni < 4; ni++)
          acc[mi][ni] = __builtin_amdgcn_mfma_f32_16x16x32_bf16(af[mi], bfr[ni], acc[mi][ni], 0, 0, 0);
    }
  }
  const float scale = (mat == 0) ? (L2E * 0.17677669529663687f) : 1.0f;
#pragma unroll
  for (int ni = 0; ni < 4; ni++) {
    int n = n0 + wn * 64 + ni * 16 + c;
    float bv_ = bias[n];
    int h = n >> 5, dd = n & 31;
#pragma unroll
    for (int mi = 0; mi < 4; mi++) {
      int mbase = m0 + wm * 64 + mi * 16 + 4 * g;
      int bb = mbase >> 10, rowL = mbase & 1023;
      int bh = bb * 8 + h;
      if (mat < 2) {
        unsigned short* out = (mat == 0) ? qx : kx;
        int m_idx = dd >> 4, hi = (dd >> 3) & 1, j = dd & 7;
#pragma unroll
        for (int r = 0; r < 4; r++) {
          int keyL = rowL + r;
          int ch = keyL >> 5, k32 = keyL & 31;
          out[(((((size_t)bh * 32 + ch) * 3 + m_idx) * 2 + hi) * 32 + k32) * 8 + j] =
              f2bf((acc[mi][ni][r] + bv_) * scale);
        }
      } else {
        int keyL = rowL;
        int ch = keyL >> 5, t = (keyL >> 4) & 1, hi = (keyL >> 3) & 1;
        size_t base = (((((size_t)bh * 32 + ch) * 2 + t) * 2 + hi) * 32 + dd) * 8 + (g & 1) * 4;
        *(uint2*)&vt2[base] =
            make_uint2(pack2(acc[mi][ni][0] + bv_, acc[mi][ni][1] + bv_),
                       pack2(acc[mi][ni][2] + bv_, acc[mi][ni][3] + bv_));
      }
    }
  }
}

// ---------------------------------------------------------------------------
// Attention (32x32x16 MFMA, physics in ext dims, no LDS, no barriers) +
// hidden weight-conversion blocks. grid 1088: p<512 attn (XCD-swizzled);
// p>=512 convert Wo/W1/W2 f32->bf16 into wts (hidden under attn).
// wts layout: [Wo 65536][W1 262144][W2 262144].
// ---------------------------------------------------------------------------
__global__ __launch_bounds__(256) void attn32(
    const unsigned short* __restrict__ qx, const unsigned short* __restrict__ kx,
    const unsigned short* __restrict__ vt2, unsigned short* __restrict__ ctx,
    const float* __restrict__ Wo, const float* __restrict__ W1,
    const float* __restrict__ W2, unsigned short* __restrict__ wts) {
  const int tid = threadIdx.x;
  const int p = blockIdx.x;
  if (p >= 512) {  // weight conversion: 576 blocks x 1024 elems
    int i = (p - 512) * 1024 + tid * 4;
    const float* src; int off;
    if (i < 65536) { src = Wo; off = i; }
    else if (i < 327680) { src = W1; off = i - 65536; }
    else { src = W2; off = i - 327680; }
    float4 v = *(const float4*)&src[off];
    *(uint2*)&wts[i] = make_uint2(pack2(v.x, v.y), pack2(v.z, v.w));
    return;
  }
  const int wave = tid >> 6, lane = tid & 63;
  const int hi = lane >> 5, l31 = lane & 31;
  const int w_id = xcd_swz(p, 64);
  const int bh = w_id >> 3, bb = bh >> 3, h = bh & 7;
  const int qch = (w_id & 7) * 4 + wave;

  const size_t qoff = (((size_t)(bh * 32 + qch) * 3 * 2 + hi) * 32 + l31) * 8;
  bf16x8 qf0 = *(const bf16x8*)&qx[qoff];
  bf16x8 qf1 = *(const bf16x8*)&qx[qoff + 512];
  bf16x8 qf2 = *(const bf16x8*)&qx[qoff + 1024];

  f32x16 acc = {};
  float mrun = 0.0f, lsum = 0.0f;

  for (int ch = 0; ch < 32; ch++) {
    const size_t koff = (((size_t)(bh * 32 + ch) * 3 * 2 + hi) * 32 + l31) * 8;
    bf16x8 kf0 = *(const bf16x8*)&kx[koff];
    bf16x8 kf1 = *(const bf16x8*)&kx[koff + 512];
    bf16x8 kf2 = *(const bf16x8*)&kx[koff + 1024];
    const size_t voff = (((size_t)(bh * 32 + ch) * 2 * 2 + hi) * 32 + l31) * 8;
    bf16x8 vf0 = *(const bf16x8*)&vt2[voff];
    bf16x8 vf1 = *(const bf16x8*)&vt2[voff + 512];

    f32x16 s = {};
    __builtin_amdgcn_s_setprio(1);
    s = __builtin_amdgcn_mfma_f32_32x32x16_bf16(kf0, qf0, s, 0, 0, 0);
    s = __builtin_amdgcn_mfma_f32_32x32x16_bf16(kf1, qf1, s, 0, 0, 0);
    s = __builtin_amdgcn_mfma_f32_32x32x16_bf16(kf2, qf2, s, 0, 0, 0);
    __builtin_amdgcn_s_setprio(0);

    float pm = fmaxf(fmaxf(fmaxf(s[0], s[1]), fmaxf(s[2], s[3])),
                     fmaxf(fmaxf(s[4], s[5]), fmaxf(s[6], s[7])));
    pm = fmaxf(pm, fmaxf(fmaxf(fmaxf(s[8], s[9]), fmaxf(s[10], s[11])),
                         fmaxf(fmaxf(s[12], s[13]), fmaxf(s[14], s[15]))));
    pm = fmaxf(pm, __shfl_xor(pm, 32, 64));
    if (__any(pm > mrun + 12.0f)) {  // rare: deferred-max rescale
      float mn = fmaxf(mrun, pm);
      float rs = fexp2(mrun - mn);
      lsum *= rs;
      mrun = mn;
#pragma unroll
      for (int r = 0; r < 16; r++) {
        float rr = __shfl(rs, (r & 3) + 8 * (r >> 2) + 4 * hi, 64);
        acc[r] *= rr;
      }
    }
    float pv[16];
#pragma unroll
    for (int r = 0; r < 16; r++) pv[r] = fexp2(s[r] - mrun);
    lsum += (((pv[0] + pv[1]) + (pv[2] + pv[3])) + ((pv[4] + pv[5]) + (pv[6] + pv[7]))) +
            (((pv[8] + pv[9]) + (pv[10] + pv[11])) + ((pv[12] + pv[13]) + (pv[14] + pv[15])));
    unsigned u0 = cvtpk(pv[0], pv[1]), u1 = cvtpk(pv[2], pv[3]);
    unsigned u2 = cvtpk(pv[4], pv[5]), u3 = cvtpk(pv[6], pv[7]);
    plswap(u0, u2); plswap(u1, u3);
    unsigned u4 = cvtpk(pv[8], pv[9]), u5 = cvtpk(pv[10], pv[11]);
    unsigned u6 = cvtpk(pv[12], pv[13]), u7 = cvtpk(pv[14], pv[15]);
    plswap(u4, u6); plswap(u5, u7);
    union { unsigned u[4]; bf16x8 v; } A1, A2;
    A1.u[0] = u0; A1.u[1] = u1; A1.u[2] = u2; A1.u[3] = u3;
    A2.u[0] = u4; A2.u[1] = u5; A2.u[2] = u6; A2.u[3] = u7;
    __builtin_amdgcn_s_setprio(1);
    acc = __builtin_amdgcn_mfma_f32_32x32x16_bf16(A1.v, vf0, acc, 0, 0, 0);
    acc = __builtin_amdgcn_mfma_f32_32x32x16_bf16(A2.v, vf1, acc, 0, 0, 0);
    __builtin_amdgcn_s_setprio(0);
  }
  lsum += __shfl_xor(lsum, 32, 64);
  float inv = 1.0f / lsum;
#pragma unroll
  for (int r = 0; r < 16; r++) {
    int qr = (r & 3) + 8 * (r >> 2) + 4 * hi;
    float rr = __shfl(inv, qr, 64);
    ctx[((size_t)bb * 1024 + qch * 32 + qr) * 256 + h * 32 + l31] = f2bf(acc[r] * rr);
  }
}

// ---------------------------------------------------------------------------
// GEMM + bias + residual + LayerNorm fused. BM=16, BN=256 (full LN rows
// in-block). 512 threads (8 waves, each 16 rows x 32 cols). grid 512
// (2 blocks/CU, 4 waves/SIMD). Validated recipe (R9).
// ---------------------------------------------------------------------------
template <int KD, int RESBF, int OUTBF>
__global__ __launch_bounds__(512) void gemm_ln(
    const unsigned short* __restrict__ A, const unsigned short* __restrict__ W,
    const float* __restrict__ bias, const void* __restrict__ resid,
    const float* __restrict__ lng, const float* __restrict__ lnb,
    void* __restrict__ out) {
  __shared__ __align__(16) unsigned short As[16 * 64];
  __shared__ __align__(16) unsigned short Bs[256 * 64];
  __shared__ float red[2][8][16];
  const int tid = threadIdx.x;
  const int w_id = xcd_swz(blockIdx.x, 64);
  const int m0 = w_id * 16;
  const int w = tid >> 6, l = tid & 63;
  const int g = (l >> 4) & 3, c = l & 15;
  const int rr = l >> 3, scol = ((l & 7) ^ rr) << 3;
  const unsigned short* aSrc = &A[(size_t)(m0 + rr) * KD + scol];
  const unsigned short* bSrc = &W[(size_t)(w * 32 + rr) * KD + scol];
  unsigned short* bDst = &Bs[w * 32 * 64];
  f32x4 acc[2] = {};
  for (int k0 = 0; k0 < KD; k0 += 64) {
    __syncthreads();
    if (w == 0) {
      gload16(aSrc + k0, &As[0]);
      gload16(aSrc + (size_t)8 * KD + k0, &As[8 * 64]);
    }
#pragma unroll
    for (int i = 0; i < 4; i++)
      gload16(bSrc + (size_t)i * 8 * KD + k0, bDst + i * 8 * 64);
    __syncthreads();
#pragma unroll
    for (int kk = 0; kk < 2; kk++) {
      bf16x8 af = *(const bf16x8*)&As[c * 64 + (((g + 4 * kk) ^ (c & 7)) << 3)];
#pragma unroll
      for (int ni = 0; ni < 2; ni++) {
        int row = w * 32 + ni * 16 + c;
        bf16x8 bfr = *(const bf16x8*)&Bs[row * 64 + (((g + 4 * kk) ^ (row & 7)) << 3)];
        acc[ni] = __builtin_amdgcn_mfma_f32_16x16x32_bf16(af, bfr, acc[ni], 0, 0, 0);
      }
    }
  }
  float x[2][4], s1[4], s2[4];
#pragma unroll
  for (int r = 0; r < 4; r++) { s1[r] = 0.0f; s2[r] = 0.0f; }
#pragma unroll
  for (int ni = 0; ni < 2; ni++) {
    int n = w * 32 + ni * 16 + c;
    float bv_ = bias[n];
#pragma unroll
    for (int r = 0; r < 4; r++) {
      int m = m0 + 4 * g + r;
      float rv = RESBF
          ? bf2f(((const unsigned short*)resid)[(size_t)m * 256 + n])
          : ((const float*)resid)[(size_t)m * 256 + n];
      float v = acc[ni][r] + bv_ + rv;
      x[ni][r] = v;
      s1[r] += v;
      s2[r] += v * v;
    }
  }
#pragma unroll
  for (int off = 1; off < 16; off <<= 1) {
#pragma unroll
    for (int r = 0; r < 4; r++) {
      s1[r] += __shfl_xor(s1[r], off, 64);
      s2[r] += __shfl_xor(s2[r], off, 64);
    }
  }
  if (c == 0) {
#pragma unroll
    for (int r = 0; r < 4; r++) {
      red[0][w][4 * g + r] = s1[r];
      red[1][w][4 * g + r] = s2[r];
    }
  }
  __syncthreads();
#pragma unroll
  for (int r = 0; r < 4; r++) {
    int row = 4 * g + r;
    float t1 = 0.0f, t2 = 0.0f;
#pragma unroll
    for (int ww = 0; ww < 8; ww++) { t1 += red[0][ww][row]; t2 += red[1][ww][row]; }
    float mean = t1 * (1.0f / 256.0f);
    float var = fmaxf(t2 * (1.0f / 256.0f) - mean * mean, 0.0f);
    float istd = rsqrtf(var + 1e-12f);
    int m = m0 + row;
#pragma unroll
    for (int ni = 0; ni < 2; ni++) {
      int n = w * 32 + ni * 16 + c;
      float o = (x[ni][r] - mean) * istd * lng[n] + lnb[n];
      if constexpr (OUTBF)
        ((unsigned short*)out)[(size_t)m * 256 + n] = f2bf(o);
      else
        ((float*)out)[(size_t)m * 256 + n] = o;
    }
  }
}

// ---------------------------------------------------------------------------
// FFN1 GEMM: BM=128, BN=128, global_load_lds staging, gelu, bf16 out.
// grid 512 (1D swz).
// ---------------------------------------------------------------------------
__global__ __launch_bounds__(256) void gemm_ffn1(
    const unsigned short* __restrict__ A, const unsigned short* __restrict__ W,
    const float* __restrict__ bias, unsigned short* __restrict__ Cout,
    int N, int K) {
  __shared__ __align__(16) unsigned short As[128 * 64];
  __shared__ __align__(16) unsigned short Bs[128 * 64];
  const int tid = threadIdx.x;
  const int w_id = xcd_swz(blockIdx.x, 64);
  const int n0 = (w_id % 8) * 128;
  const int m0 = (w_id / 8) * 128;
  const int wm = (tid >> 7) & 1, wn = (tid >> 6) & 1;
  const int g = (tid >> 4) & 3, c = tid & 15;
  const int l = tid & 63, wv = tid >> 6;
  const int rr = l >> 3, scol = ((l & 7) ^ rr) << 3;
  const unsigned short* aSrc = &A[(size_t)(m0 + wv * 32 + rr) * K + scol];
  const unsigned short* bSrc = &W[(size_t)(n0 + wv * 32 + rr) * K + scol];
  unsigned short* aDst = &As[wv * 32 * 64];
  unsigned short* bDst = &Bs[wv * 32 * 64];
  f32x4 acc[4][4] = {};
  for (int k0 = 0; k0 < K; k0 += 64) {
    __syncthreads();
#pragma unroll
    for (int i = 0; i < 4; i++) {
      gload16(aSrc + (size_t)i * 8 * K + k0, aDst + i * 8 * 64);
      gload16(bSrc + (size_t)i * 8 * K + k0, bDst + i * 8 * 64);
    }
    __syncthreads();
#pragma unroll
    for (int kk = 0; kk < 2; kk++) {
      bf16x8 af[4], bfr[4];
#pragma unroll
      for (int mi = 0; mi < 4; mi++) {
        int row = wm * 64 + mi * 16 + c;
        af[mi] = *(const bf16x8*)&As[row * 64 + (((g + 4 * kk) ^ (row & 7)) << 3)];
      }
#pragma unroll
      for (int ni = 0; ni < 4; ni++) {
        int row = wn * 64 + ni * 16 + c;
        bfr[ni] = *(const bf16x8*)&Bs[row * 64 + (((g + 4 * kk) ^ (row & 7)) << 3)];
      }
#pragma unroll
      for (int mi = 0; mi < 4; mi++)
#pragma unroll
        for (int ni = 0; ni < 4; ni++)
          acc[mi][ni] = __builtin_amdgcn_mfma_f32_16x16x32_bf16(af[mi], bfr[ni], acc[mi][ni], 0, 0, 0);
    }
  }
#pragma unroll
  for (int ni = 0; ni < 4; ni++) {
    int n = n0 + wn * 64 + ni * 16 + c;
    float bv_ = bias[n];
#pragma unroll
    for (int mi = 0; mi < 4; mi++) {
      int mbase = m0 + wm * 64 + mi * 16 + 4 * g;
#pragma unroll
      for (int r = 0; r < 4; r++) {
        int m = mbase + r;
        float x = acc[mi][ni][r] + bv_;
        Cout[(size_t)m * N + n] =
            f2bf(x * 0.5f * (1.0f + erff(x * 0.70710678118654752f)));
      }
    }
  }
}

// ---------------------------------------------------------------------------
extern "C" void kernel_launch(void* const* d_in, const int* in_sizes, int n_in,
                              void* d_out, int out_size, void* d_ws,
                              size_t ws_size, hipStream_t stream) {
  const float* hs = (const float*)d_in[0];
  const float* mask = (const float*)d_in[1];
  const float* phi = (const float*)d_in[2];
  const float* mag = (const float*)d_in[3];
  const float* Wq = (const float*)d_in[4];
  const float* bq = (const float*)d_in[5];
  const float* Wk = (const float*)d_in[6];
  const float* bk = (const float*)d_in[7];
  const float* Wv = (const float*)d_in[8];
  const float* bv = (const float*)d_in[9];
  const float* Wo = (const float*)d_in[10];
  const float* bo = (const float*)d_in[11];
  const float* ln1g = (const float*)d_in[12];
  const float* ln1b = (const float*)d_in[13];
  const float* gamma = (const float*)d_in[14];
  const float* W1 = (const float*)d_in[15];
  const float* b1 = (const float*)d_in[16];
  const float* W2 = (const float*)d_in[17];
  const float* b2 = (const float*)d_in[18];
  const float* ln2g = (const float*)d_in[19];
  const float* ln2b = (const float*)d_in[20];

  char* wsb = (char*)d_ws;
  unsigned short* wts = (unsigned short*)(wsb + 0);              // 1.2MB: Wo|W1|W2
  unsigned short* ctx = (unsigned short*)(wsb + (6ull << 20));   // 4MB
  unsigned short* aout = (unsigned short*)(wsb + (10ull << 20)); // 4MB
  unsigned short* qx = (unsigned short*)(wsb + (22ull << 20));   // 6MB
  unsigned short* kx = (unsigned short*)(wsb + (28ull << 20));   // 6MB
  unsigned short* vt2 = (unsigned short*)(wsb + (34ull << 20));  // 4MB
  unsigned short* hbuf = (unsigned short*)(wsb + (40ull << 20)); // 16MB

  dim3 blk(256);
  // QKV (f32 pack-on-stage) + physics ext-slab fill
  gemm_qkv<<<dim3(448), blk, 0, stream>>>(hs, Wq, Wk, Wv, bq, bk, bv, phi,
                                          mag, mask, gamma, qx, kx, vt2);
  // attention + hidden Wo/W1/W2 f32->bf16 conversion
  attn32<<<dim3(1088), blk, 0, stream>>>(qx, kx, vt2, ctx, Wo, W1, W2, wts);
  // Wo + residual(hs,f32) + LN1 -> aout (bf16)
  gemm_ln<256, 0, 1><<<dim3(512), dim3(512), 0, stream>>>(
      ctx, wts, bo, hs, ln1g, ln1b, aout);
  // FFN1 + gelu -> hbuf (bf16)
  gemm_ffn1<<<dim3(512), blk, 0, stream>>>(aout, wts + 65536, b1, hbuf, 1024, 256);
  // FFN2 + residual(aout,bf16) + LN2 -> d_out (f32)
  gemm_ln<1024, 1, 0><<<dim3(512), dim3(512), 0, stream>>>(
      hbuf, wts + 327680, b2, aout, ln2g, ln2b, d_out);
}